// Round 5
// baseline (421.817 us; speedup 1.0000x reference)
//
#include <hip/hip_runtime.h>
#include <cstddef>

#define BB 8
#define CC 512
#define LL 2048
#define TT 64

typedef short short8 __attribute__((ext_vector_type(8)));
typedef float floatx4 __attribute__((ext_vector_type(4)));
typedef unsigned short b16u;
typedef unsigned int u32;

static __device__ __forceinline__ unsigned f2bfu(float f) {
    unsigned u = __float_as_uint(f);
    u += 0x7fffu + ((u >> 16) & 1u);          // round-to-nearest-even
    return u >> 16;
}

#define MFMA16(a, b, c) __builtin_amdgcn_mfma_f32_16x16x32_bf16((a), (b), (c), 0, 0, 0)

// async 16B global->LDS (DMA, no VGPR round trip). LDS dest must be
// wave-uniform base; HW adds lane*16.
static __device__ __forceinline__ void gl2lds16(const void* g, void* l) {
    __builtin_amdgcn_global_load_lds(
        (const __attribute__((address_space(1))) u32*)g,
        (__attribute__((address_space(3))) u32*)l, 16, 0, 0);
}

// ---------------------------------------------------------------------------
// K0: transpose W1,W2 (64t x 512c fp32) -> WT1,WT2 (512c x 64t fp32).
// Tiny (256 KB); enables lane-uniform 64B W loads in qk_kernel.
// ---------------------------------------------------------------------------
__global__ __launch_bounds__(256) void wprep_kernel(
    const float* __restrict__ W1, const float* __restrict__ W2,
    float* __restrict__ WT1, float* __restrict__ WT2)
{
    int flat = blockIdx.x * 256 + threadIdx.x;    // 0..32767
    int c = flat >> 6, t = flat & 63;
    WT1[flat] = W1[t * 512 + c];
    WT2[flat] = W2[t * 512 + c];
}

// ---------------------------------------------------------------------------
// K1: Q,K projection on the VECTOR ALU -- no LDS, no barriers, no transpose.
// Q[t][l] = sum_c W1[t][c] x[c][l]: lane = l (x dword loads coalesced),
// W broadcast lane-uniform from WT[c][t] (L2-hot 64B loads), 16 t per block
// (t-quarter) -> 32 fp32 accumulators = deep ILP.  fp32 accumulation
// (better than the old split-bf16 path), bf16 cast at the end.
// grid 256 (bid&7 = batch -> XCD L2 locality), 256 thr, 1 block/CU.
// ---------------------------------------------------------------------------
__global__ __launch_bounds__(256, 4) void qk_kernel(
    const float* __restrict__ x,
    const float* __restrict__ WT1, const float* __restrict__ WT2,
    b16u* __restrict__ Qt, b16u* __restrict__ Kt)
{
    const int bid = blockIdx.x;
    const int b  = bid & 7;
    const int lt = (bid >> 3) & 7;
    const int tq = bid >> 6;                       // t-quarter 0..3
    const int l  = lt * 256 + threadIdx.x;
    const float* xb = x + (size_t)b * CC * LL + l; // + c*LL per c
    const float* w1 = WT1 + tq * 16;               // + c*64 per c
    const float* w2 = WT2 + tq * 16;

    float qa[16], ka[16];
#pragma unroll
    for (int t = 0; t < 16; ++t) { qa[t] = 0.f; ka[t] = 0.f; }

    float4 wqA[4], wkA[4], wqB[4], wkB[4];
    float xA, xB;

#define QKLOAD(WQ, WK, XV, C)                                              \
    {                                                                      \
        const float* p1 = w1 + (size_t)(C) * 64;                           \
        const float* p2 = w2 + (size_t)(C) * 64;                           \
        WQ[0] = *(const float4*)(p1);                                      \
        WQ[1] = *(const float4*)(p1 + 4);                                  \
        WQ[2] = *(const float4*)(p1 + 8);                                  \
        WQ[3] = *(const float4*)(p1 + 12);                                 \
        WK[0] = *(const float4*)(p2);                                      \
        WK[1] = *(const float4*)(p2 + 4);                                  \
        WK[2] = *(const float4*)(p2 + 8);                                  \
        WK[3] = *(const float4*)(p2 + 12);                                 \
        XV = xb[(size_t)(C) * LL];                                         \
    }
#define QKFMA(WQ, WK, XV)                                                  \
    {                                                                      \
        _Pragma("unroll")                                                  \
        for (int t = 0; t < 16; ++t) {                                     \
            qa[t] += ((const float*)&WQ[t >> 2])[t & 3] * XV;              \
            ka[t] += ((const float*)&WK[t >> 2])[t & 3] * XV;              \
        }                                                                  \
    }

    QKLOAD(wqA, wkA, xA, 0)
    for (int c = 0; c < 512; c += 2) {
        if (c + 1 < 512) QKLOAD(wqB, wkB, xB, c + 1)
        QKFMA(wqA, wkA, xA)
        if (c + 2 < 512) QKLOAD(wqA, wkA, xA, c + 2)
        QKFMA(wqB, wkB, xB)
    }
#undef QKLOAD
#undef QKFMA

    // Qt/Kt layout (b, l, 64t) bf16 -- what pexp consumes.
    b16u* qo = Qt + ((size_t)(b * LL) + l) * 64 + tq * 16;
    b16u* ko = Kt + ((size_t)(b * LL) + l) * 64 + tq * 16;
#pragma unroll
    for (int p = 0; p < 8; ++p) {
        *(u32*)(qo + p * 2) = f2bfu(qa[p * 2]) | (f2bfu(qa[p * 2 + 1]) << 16);
        *(u32*)(ko + p * 2) = f2bfu(ka[p * 2]) | (f2bfu(ka[p * 2 + 1]) << 16);
    }
}

// ---------------------------------------------------------------------------
// K2: x -> XT (b, iblk, c, 64) bf16, 16B-chunk XOR-swizzled (key = c&7).
// grid (32 i-tiles, 8 c-tiles, 8 b), block 256.  (R0 verbatim)
// ---------------------------------------------------------------------------
__global__ __launch_bounds__(256) void xcvt_kernel(
    const float* __restrict__ x, b16u* __restrict__ XT)
{
    const int b = blockIdx.z, c0 = blockIdx.y * 64, it = blockIdx.x;
    const int tid = threadIdx.x;
#pragma unroll
    for (int p = 0; p < 4; ++p) {
        int flat = tid + p * 256;                 // 0..1023: 64 c x 16 groups
        int c = flat >> 4, s = flat & 15;
        float4 v = *(const float4*)(x + ((size_t)(b * 512) + c0 + c) * 2048 + it * 64 + s * 4);
        uint2 wv;
        wv.x = f2bfu(v.x) | (f2bfu(v.y) << 16);
        wv.y = f2bfu(v.z) | (f2bfu(v.w) << 16);
        int phys = (((s >> 1) ^ (c & 7)) << 3) + ((s & 1) << 2);   // shorts
        *(uint2*)(XT + (((size_t)(b * 32) + it) * 512 + c0 + c) * 64 + phys) = wv;
    }
}

// ---------------------------------------------------------------------------
// K3: P (swizzled (pb, iblk, j, 64)) = bf16(exp(S-20)), Zpart = row sums.
// (R0 verbatim)  grid (2 i-halves, 32 j-tiles, nb).
// ---------------------------------------------------------------------------
__global__ __launch_bounds__(256) void pexp_kernel(
    const b16u* __restrict__ Qt, const b16u* __restrict__ Kt,
    b16u* __restrict__ P, float* __restrict__ Zpart, int b_off)
{
    __shared__ b16u Ks[64 * 72];    // [i][t]
    __shared__ b16u Ls[64 * 68];    // [j][i] staging
    __shared__ float Zw[4][64];
    const int pb = blockIdx.z, b = b_off + pb;
    const int j0 = blockIdx.y * 64;
    const int ibase = blockIdx.x * 1024;
    const int tid = threadIdx.x;
    const int lane = tid & 63;
    const int w = tid >> 6;
    const int n16 = lane & 15;
    const int qd = lane >> 4;
    const b16u* kb = Kt + (size_t)b * (2048 * 64);

    short8 qf[4][2];                // Q B-fragments, loop-invariant
#pragma unroll
    for (int nt = 0; nt < 4; ++nt)
#pragma unroll
        for (int kc = 0; kc < 2; ++kc)
            qf[nt][kc] = *(const short8*)(Qt +
                ((size_t)(b * 2048) + j0 + nt * 16 + n16) * 64 + kc * 32 + qd * 8);

    uint4 kreg[2];
#pragma unroll
    for (int p = 0; p < 2; ++p) {
        int flat = tid + p * 256;
        kreg[p] = *(const uint4*)(kb + (size_t)(ibase + (flat >> 3)) * 64 + (flat & 7) * 8);
    }
    float zacc[4] = {0.f, 0.f, 0.f, 0.f};

    for (int it = 0; it < 16; ++it) {
#pragma unroll
        for (int p = 0; p < 2; ++p) {
            int flat = tid + p * 256;
            *(uint4*)&Ks[(flat >> 3) * 72 + (flat & 7) * 8] = kreg[p];
        }
        {
            const int itn = (it + 1 < 16) ? it + 1 : 15;
#pragma unroll
            for (int p = 0; p < 2; ++p) {
                int flat = tid + p * 256;
                kreg[p] = *(const uint4*)(kb +
                    (size_t)(ibase + itn * 64 + (flat >> 3)) * 64 + (flat & 7) * 8);
            }
        }
        __syncthreads();
        floatx4 sacc[4];
#pragma unroll
        for (int nt = 0; nt < 4; ++nt) sacc[nt] = (floatx4){0.f, 0.f, 0.f, 0.f};
#pragma unroll
        for (int kc = 0; kc < 2; ++kc) {
            short8 af = *(const short8*)&Ks[(w * 16 + n16) * 72 + kc * 32 + qd * 8];
#pragma unroll
            for (int nt = 0; nt < 4; ++nt)
                sacc[nt] = MFMA16(af, qf[nt][kc], sacc[nt]);
        }
        // lane: j = j0+nt*16+n16 (col), i-local = w*16+qd*4+r (row)
#pragma unroll
        for (int nt = 0; nt < 4; ++nt) {
            float p0 = __expf(sacc[nt][0] - 20.0f);
            float p1 = __expf(sacc[nt][1] - 20.0f);
            float p2 = __expf(sacc[nt][2] - 20.0f);
            float p3 = __expf(sacc[nt][3] - 20.0f);
            zacc[nt] += (p0 + p1) + (p2 + p3);
            uint2 pk;
            pk.x = f2bfu(p0) | (f2bfu(p1) << 16);
            pk.y = f2bfu(p2) | (f2bfu(p3) << 16);
            *(uint2*)&Ls[(nt * 16 + n16) * 68 + w * 16 + qd * 4] = pk;
        }
        __syncthreads();
        // coalesced swizzled P write: 64 rows (j) x 128 B
        size_t prow = ((size_t)(pb * 32) + (ibase >> 6) + it) * 2048 + j0;
#pragma unroll
        for (int p = 0; p < 4; ++p) {
            int u = tid + p * 256;
            int row = u >> 4, s = u & 15;
            int phys = (((s >> 1) ^ (row & 7)) << 3) + ((s & 1) << 2);
            *(uint2*)(P + (prow + row) * 64 + phys) = *(const uint2*)&Ls[row * 68 + s * 4];
        }
    }
    // z: reduce over qd (i within wave), then over waves via LDS
#pragma unroll
    for (int nt = 0; nt < 4; ++nt) {
        float z = zacc[nt];
        z += __shfl_xor(z, 16);
        z += __shfl_xor(z, 32);
        if (qd == 0) Zw[w][nt * 16 + n16] = z;
    }
    __syncthreads();
    if (tid < 64) {
        float s = Zw[0][tid] + Zw[1][tid] + Zw[2][tid] + Zw[3][tid];
        Zpart[((size_t)blockIdx.x * 8 + b) * 2048 + j0 + tid] = s;
    }
}

// ---------------------------------------------------------------------------
// K4: out = x + gamma * zinv * (XT @ P^T).  (R0 verbatim)
// grid (16 j, 4 c, nb), block 256; wave = 64c x 64j quadrant.
// ---------------------------------------------------------------------------
__global__ __launch_bounds__(256, 2) void gemm_kernel(
    const float* __restrict__ x, const b16u* __restrict__ XT,
    const b16u* __restrict__ P, const float* __restrict__ Zpart,
    const float* __restrict__ gamma, float* __restrict__ out, int b_off)
{
    __shared__ __align__(16) char smem[69632];
    b16u* As = (b16u*)smem;               // [2][8192] shorts
    b16u* Bs = (b16u*)(smem + 32768);     // [2][8192]
    const int pb = blockIdx.z, b = b_off + pb;
    const int j0 = blockIdx.x * 128;
    const int c0 = blockIdx.y * 128;
    const int tid = threadIdx.x;
    const int lane = tid & 63;
    const int w = tid >> 6;
    const int n16 = lane & 15;
    const int qd = lane >> 4;
    const int wc = w & 1;
    const int wj = w >> 1;

    const b16u* tA = XT + ((size_t)(b * 32) * 512 + c0) * 64 + w * 2048 + lane * 8;
    const b16u* tB = P + ((size_t)(pb * 32) * 2048 + j0) * 64 + w * 2048 + lane * 8;
    b16u* lA = As + w * 2048;
    b16u* lB = Bs + w * 2048;

#define STAGE(IT, BUF)                                                    \
    {                                                                      \
        const b16u* ga = tA + (size_t)(IT) * 32768;                        \
        const b16u* gb = tB + (size_t)(IT) * 131072;                       \
        _Pragma("unroll")                                                  \
        for (int ch = 0; ch < 4; ++ch) {                                   \
            gl2lds16(ga + ch * 512, lA + (BUF) * 8192 + ch * 512);         \
            gl2lds16(gb + ch * 512, lB + (BUF) * 8192 + ch * 512);         \
        }                                                                  \
    }

    STAGE(0, 0)
    __syncthreads();

    floatx4 acc[4][4];
#pragma unroll
    for (int mt = 0; mt < 4; ++mt)
#pragma unroll
        for (int nt = 0; nt < 4; ++nt) acc[mt][nt] = (floatx4){0.f, 0.f, 0.f, 0.f};

    for (int it = 0; it < 32; ++it) {
        const int buf = it & 1;
        if (it < 31) STAGE(it + 1, buf ^ 1)
        const b16u* Ab = As + buf * 8192;
        const b16u* Bb = Bs + buf * 8192;
#pragma unroll
        for (int kc = 0; kc < 2; ++kc) {
            const int co = (((kc * 4 + qd) ^ (n16 & 7)) << 3);   // phys chunk offset
            short8 af[4], bf[4];
#pragma unroll
            for (int mt = 0; mt < 4; ++mt)
                af[mt] = *(const short8*)&Ab[(wc * 64 + mt * 16 + n16) * 64 + co];
#pragma unroll
            for (int nt = 0; nt < 4; ++nt)
                bf[nt] = *(const short8*)&Bb[(wj * 64 + nt * 16 + n16) * 64 + co];
#pragma unroll
            for (int mt = 0; mt < 4; ++mt)
#pragma unroll
                for (int nt = 0; nt < 4; ++nt)
                    acc[mt][nt] = MFMA16(af[mt], bf[nt], acc[mt][nt]);
        }
        __syncthreads();
    }
#undef STAGE

    // ---- epilogue: scale by g*zinv, stage per-wave quadrant, coalesced out ----
    const float g = gamma[0];
    float* st = (float*)(smem + w * 17408);       // 64 x 68 floats per wave
#pragma unroll
    for (int nt = 0; nt < 4; ++nt) {
        int j = j0 + wj * 64 + nt * 16 + n16;
        float zi = g / (Zpart[(size_t)b * 2048 + j] +
                        Zpart[16384 + (size_t)b * 2048 + j]);
#pragma unroll
        for (int mt = 0; mt < 4; ++mt)
#pragma unroll
            for (int r = 0; r < 4; ++r)
                st[(mt * 16 + qd * 4 + r) * 68 + nt * 16 + n16] = acc[mt][nt][r] * zi;
    }
    __syncthreads();
#pragma unroll
    for (int p = 0; p < 16; ++p) {
        int rl = qd * 16 + p;                     // c-local row in quadrant
        int cg = c0 + wc * 64 + rl;
        size_t go = ((size_t)(b * 512) + cg) * 2048 + j0 + wj * 64 + n16 * 4;
        float4 v = *(const float4*)&st[rl * 68 + n16 * 4];
        float4 xv = *(const float4*)(x + go);
        v.x += xv.x; v.y += xv.y; v.z += xv.z; v.w += xv.w;
        *(float4*)(out + go) = v;
    }
}

// ---------------------------------------------------------------------------
extern "C" void kernel_launch(void* const* d_in, const int* in_sizes, int n_in,
                              void* d_out, int out_size, void* d_ws, size_t ws_size,
                              hipStream_t stream)
{
    (void)in_sizes; (void)n_in; (void)out_size;
    const float* x     = (const float*)d_in[0];
    const float* W1    = (const float*)d_in[1];
    const float* W2    = (const float*)d_in[2];
    const float* gamma = (const float*)d_in[3];
    float* out = (float*)d_out;

    b16u*  Qt  = (b16u*)d_ws;                       // 2 MB
    b16u*  Kt  = Qt + (size_t)BB * LL * TT;         // 2 MB
    float* WT1 = (float*)(Kt + (size_t)BB * LL * TT);   // 128 KB
    float* WT2 = WT1 + (size_t)TT * CC;                 // 128 KB
    float* Zp  = WT2 + (size_t)TT * CC;             // 128 KB
    b16u*  XT  = (b16u*)(Zp + 2 * 8 * 2048);        // 16.8 MB
    b16u*  P   = XT + (size_t)BB * 32 * 512 * 64;   // nb * 8.39 MB

    const size_t base = (size_t)((char*)P - (char*)d_ws);
    const size_t pbat = (size_t)LL * LL * 2;
    int nb = 8;
    if (ws_size < base + 8 * pbat) nb = 4;
    if (ws_size < base + 4 * pbat) nb = 2;
    if (ws_size < base + 2 * pbat) nb = 1;

    wprep_kernel<<<dim3(128),       256, 0, stream>>>(W1, W2, WT1, WT2);
    qk_kernel   <<<dim3(256),       256, 0, stream>>>(x, WT1, WT2, Qt, Kt);
    xcvt_kernel <<<dim3(32, 8, BB), 256, 0, stream>>>(x, XT);
    for (int b0 = 0; b0 < BB; b0 += nb) {
        pexp_kernel<<<dim3(2, 32, nb), 256, 0, stream>>>(Qt, Kt, P, Zp, b0);
        gemm_kernel<<<dim3(16, 4, nb), 256, 0, stream>>>(x, XT, P, Zp, gamma, out, b0);
    }
}

// Round 6
// 228.902 us; speedup vs baseline: 1.8428x; 1.8428x over previous
//
#include <hip/hip_runtime.h>
#include <cstddef>

#define BB 8
#define CC 512
#define LL 2048
#define TT 64

typedef short short8 __attribute__((ext_vector_type(8)));
typedef float floatx4 __attribute__((ext_vector_type(4)));
typedef unsigned short b16u;
typedef unsigned int u32;

static __device__ __forceinline__ unsigned f2bfu(float f) {
    unsigned u = __float_as_uint(f);
    u += 0x7fffu + ((u >> 16) & 1u);          // round-to-nearest-even
    return u >> 16;
}

#define MFMA16(a, b, c) __builtin_amdgcn_mfma_f32_16x16x32_bf16((a), (b), (c), 0, 0, 0)

// async 16B global->LDS (DMA, no VGPR round trip). LDS dest must be
// wave-uniform base; HW adds lane*16.
static __device__ __forceinline__ void gl2lds16(const void* g, void* l) {
    __builtin_amdgcn_global_load_lds(
        (const __attribute__((address_space(1))) u32*)g,
        (__attribute__((address_space(3))) u32*)l, 16, 0, 0);
}

// ---------------------------------------------------------------------------
// K0: transpose W1,W2 (64t x 512c fp32) -> WT1,WT2 (512c x 64t fp32).
// ---------------------------------------------------------------------------
__global__ __launch_bounds__(256) void wprep_kernel(
    const float* __restrict__ W1, const float* __restrict__ W2,
    float* __restrict__ WT1, float* __restrict__ WT2)
{
    int flat = blockIdx.x * 256 + threadIdx.x;    // 0..32767
    int c = flat >> 6, t = flat & 63;
    WT1[flat] = W1[t * 512 + c];
    WT2[flat] = W2[t * 512 + c];
}

// ---------------------------------------------------------------------------
// K1: Q,K projection on the VECTOR ALU.  R5 failed from register
// mismanagement (VGPR=24, address-taken vectors) + 1 wave/SIMD + 2-deep
// pipeline.  Fix: W slice in LDS (broadcast ds_read_b128, conflict-free),
// x prefetched 8-deep in registers, all accesses constant-indexed,
// grid 512 = 2 blocks/CU (2 waves/SIMD).  bid = b + 8*(tb + 8*lt) so the
// 8 t-group blocks sharing an x panel run adjacently on the same XCD.
// Per thread: l fixed, 8 t values, 16 fp32 accum; 16 FMA per c.
// ---------------------------------------------------------------------------
__global__ __launch_bounds__(256) void qk_kernel(
    const float* __restrict__ x,
    const float* __restrict__ WT1, const float* __restrict__ WT2,
    b16u* __restrict__ Qt, b16u* __restrict__ Kt)
{
    __shared__ float Ws[512 * 16];   // [c][0..7 = W1 slice, 8..15 = W2 slice]
    const int bid = blockIdx.x;
    const int b  = bid & 7;
    const int tb = (bid >> 3) & 7;        // t-group: t in [tb*8, tb*8+8)
    const int lt = bid >> 6;              // l-chunk of 256
    const int tid = threadIdx.x;
    const int l = lt * 256 + tid;
    const float* xb = x + (size_t)b * CC * LL + l;

    // stage W slices: 8192 dwords, 32 per thread
#pragma unroll
    for (int k = 0; k < 32; ++k) {
        int flat = tid + k * 256;          // = c*16 + j
        int c = flat >> 4, j = flat & 15;
        const float* src = (j < 8) ? WT1 : WT2;
        Ws[flat] = src[c * 64 + tb * 8 + (j & 7)];
    }
    __syncthreads();

    float qa[8], ka[8];
#pragma unroll
    for (int t = 0; t < 8; ++t) { qa[t] = 0.f; ka[t] = 0.f; }

    float xv[8], xn[8];
#pragma unroll
    for (int p = 0; p < 8; ++p) xv[p] = xb[(size_t)p * LL];

    for (int c0 = 0; c0 < 512; c0 += 8) {
        if (c0 + 8 < 512) {
#pragma unroll
            for (int p = 0; p < 8; ++p) xn[p] = xb[(size_t)(c0 + 8 + p) * LL];
        }
#pragma unroll
        for (int cc = 0; cc < 8; ++cc) {
            const floatx4* wp = (const floatx4*)&Ws[(c0 + cc) * 16];
            floatx4 q0 = wp[0], q1 = wp[1];
            floatx4 k0 = wp[2], k1 = wp[3];
            float xs = xv[cc];
#pragma unroll
            for (int t = 0; t < 4; ++t) {
                qa[t]     += q0[t] * xs;
                qa[t + 4] += q1[t] * xs;
                ka[t]     += k0[t] * xs;
                ka[t + 4] += k1[t] * xs;
            }
        }
#pragma unroll
        for (int p = 0; p < 8; ++p) xv[p] = xn[p];
    }

    // Qt/Kt layout (b, l, 64t) bf16 -- what pexp consumes.
    b16u* qo = Qt + ((size_t)(b * LL) + l) * 64 + tb * 8;
    b16u* ko = Kt + ((size_t)(b * LL) + l) * 64 + tb * 8;
    uint4 qw, kw;
    qw.x = f2bfu(qa[0]) | (f2bfu(qa[1]) << 16);
    qw.y = f2bfu(qa[2]) | (f2bfu(qa[3]) << 16);
    qw.z = f2bfu(qa[4]) | (f2bfu(qa[5]) << 16);
    qw.w = f2bfu(qa[6]) | (f2bfu(qa[7]) << 16);
    kw.x = f2bfu(ka[0]) | (f2bfu(ka[1]) << 16);
    kw.y = f2bfu(ka[2]) | (f2bfu(ka[3]) << 16);
    kw.z = f2bfu(ka[4]) | (f2bfu(ka[5]) << 16);
    kw.w = f2bfu(ka[6]) | (f2bfu(ka[7]) << 16);
    *(uint4*)qo = qw;
    *(uint4*)ko = kw;
}

// ---------------------------------------------------------------------------
// K2: x -> XT (b, iblk, c, 64) bf16, 16B-chunk XOR-swizzled (key = c&7).
// grid (32 i-tiles, 8 c-tiles, 8 b), block 256.  (R0 verbatim)
// ---------------------------------------------------------------------------
__global__ __launch_bounds__(256) void xcvt_kernel(
    const float* __restrict__ x, b16u* __restrict__ XT)
{
    const int b = blockIdx.z, c0 = blockIdx.y * 64, it = blockIdx.x;
    const int tid = threadIdx.x;
#pragma unroll
    for (int p = 0; p < 4; ++p) {
        int flat = tid + p * 256;                 // 0..1023: 64 c x 16 groups
        int c = flat >> 4, s = flat & 15;
        float4 v = *(const float4*)(x + ((size_t)(b * 512) + c0 + c) * 2048 + it * 64 + s * 4);
        uint2 wv;
        wv.x = f2bfu(v.x) | (f2bfu(v.y) << 16);
        wv.y = f2bfu(v.z) | (f2bfu(v.w) << 16);
        int phys = (((s >> 1) ^ (c & 7)) << 3) + ((s & 1) << 2);   // shorts
        *(uint2*)(XT + (((size_t)(b * 32) + it) * 512 + c0 + c) * 64 + phys) = wv;
    }
}

// ---------------------------------------------------------------------------
// K3: P (swizzled (pb, iblk, j, 64)) = bf16(exp(S-20)), Zpart = row sums.
// i-split 2 -> 4 (grid (4, 32, nb), 4 blocks/CU) for occupancy; Zpart now
// 4 partials per (b, j).  Otherwise R0 verbatim.
// ---------------------------------------------------------------------------
__global__ __launch_bounds__(256) void pexp_kernel(
    const b16u* __restrict__ Qt, const b16u* __restrict__ Kt,
    b16u* __restrict__ P, float* __restrict__ Zpart, int b_off)
{
    __shared__ b16u Ks[64 * 72];    // [i][t]
    __shared__ b16u Ls[64 * 68];    // [j][i] staging
    __shared__ float Zw[4][64];
    const int pb = blockIdx.z, b = b_off + pb;
    const int j0 = blockIdx.y * 64;
    const int ibase = blockIdx.x * 512;
    const int tid = threadIdx.x;
    const int lane = tid & 63;
    const int w = tid >> 6;
    const int n16 = lane & 15;
    const int qd = lane >> 4;
    const b16u* kb = Kt + (size_t)b * (2048 * 64);

    short8 qf[4][2];                // Q B-fragments, loop-invariant
#pragma unroll
    for (int nt = 0; nt < 4; ++nt)
#pragma unroll
        for (int kc = 0; kc < 2; ++kc)
            qf[nt][kc] = *(const short8*)(Qt +
                ((size_t)(b * 2048) + j0 + nt * 16 + n16) * 64 + kc * 32 + qd * 8);

    uint4 kreg[2];
#pragma unroll
    for (int p = 0; p < 2; ++p) {
        int flat = tid + p * 256;
        kreg[p] = *(const uint4*)(kb + (size_t)(ibase + (flat >> 3)) * 64 + (flat & 7) * 8);
    }
    float zacc[4] = {0.f, 0.f, 0.f, 0.f};

    for (int it = 0; it < 8; ++it) {
#pragma unroll
        for (int p = 0; p < 2; ++p) {
            int flat = tid + p * 256;
            *(uint4*)&Ks[(flat >> 3) * 72 + (flat & 7) * 8] = kreg[p];
        }
        {
            const int itn = (it + 1 < 8) ? it + 1 : 7;
#pragma unroll
            for (int p = 0; p < 2; ++p) {
                int flat = tid + p * 256;
                kreg[p] = *(const uint4*)(kb +
                    (size_t)(ibase + itn * 64 + (flat >> 3)) * 64 + (flat & 7) * 8);
            }
        }
        __syncthreads();
        floatx4 sacc[4];
#pragma unroll
        for (int nt = 0; nt < 4; ++nt) sacc[nt] = (floatx4){0.f, 0.f, 0.f, 0.f};
#pragma unroll
        for (int kc = 0; kc < 2; ++kc) {
            short8 af = *(const short8*)&Ks[(w * 16 + n16) * 72 + kc * 32 + qd * 8];
#pragma unroll
            for (int nt = 0; nt < 4; ++nt)
                sacc[nt] = MFMA16(af, qf[nt][kc], sacc[nt]);
        }
        // lane: j = j0+nt*16+n16 (col), i-local = w*16+qd*4+r (row)
#pragma unroll
        for (int nt = 0; nt < 4; ++nt) {
            float p0 = __expf(sacc[nt][0] - 20.0f);
            float p1 = __expf(sacc[nt][1] - 20.0f);
            float p2 = __expf(sacc[nt][2] - 20.0f);
            float p3 = __expf(sacc[nt][3] - 20.0f);
            zacc[nt] += (p0 + p1) + (p2 + p3);
            uint2 pk;
            pk.x = f2bfu(p0) | (f2bfu(p1) << 16);
            pk.y = f2bfu(p2) | (f2bfu(p3) << 16);
            *(uint2*)&Ls[(nt * 16 + n16) * 68 + w * 16 + qd * 4] = pk;
        }
        __syncthreads();
        // coalesced swizzled P write: 64 rows (j) x 128 B
        size_t prow = ((size_t)(pb * 32) + (ibase >> 6) + it) * 2048 + j0;
#pragma unroll
        for (int p = 0; p < 4; ++p) {
            int u = tid + p * 256;
            int row = u >> 4, s = u & 15;
            int phys = (((s >> 1) ^ (row & 7)) << 3) + ((s & 1) << 2);
            *(uint2*)(P + (prow + row) * 64 + phys) = *(const uint2*)&Ls[row * 68 + s * 4];
        }
    }
    // z: reduce over qd (i within wave), then over waves via LDS
#pragma unroll
    for (int nt = 0; nt < 4; ++nt) {
        float z = zacc[nt];
        z += __shfl_xor(z, 16);
        z += __shfl_xor(z, 32);
        if (qd == 0) Zw[w][nt * 16 + n16] = z;
    }
    __syncthreads();
    if (tid < 64) {
        float s = Zw[0][tid] + Zw[1][tid] + Zw[2][tid] + Zw[3][tid];
        Zpart[((size_t)blockIdx.x * 8 + b) * 2048 + j0 + tid] = s;
    }
}

// ---------------------------------------------------------------------------
// K4: out = x + gamma * zinv * (XT @ P^T).  (R0 verbatim; Z = sum of 4
// partials now.)  grid (16 j, 4 c, nb), block 256.
// ---------------------------------------------------------------------------
__global__ __launch_bounds__(256, 2) void gemm_kernel(
    const float* __restrict__ x, const b16u* __restrict__ XT,
    const b16u* __restrict__ P, const float* __restrict__ Zpart,
    const float* __restrict__ gamma, float* __restrict__ out, int b_off)
{
    __shared__ __align__(16) char smem[69632];
    b16u* As = (b16u*)smem;               // [2][8192] shorts
    b16u* Bs = (b16u*)(smem + 32768);     // [2][8192]
    const int pb = blockIdx.z, b = b_off + pb;
    const int j0 = blockIdx.x * 128;
    const int c0 = blockIdx.y * 128;
    const int tid = threadIdx.x;
    const int lane = tid & 63;
    const int w = tid >> 6;
    const int n16 = lane & 15;
    const int qd = lane >> 4;
    const int wc = w & 1;
    const int wj = w >> 1;

    const b16u* tA = XT + ((size_t)(b * 32) * 512 + c0) * 64 + w * 2048 + lane * 8;
    const b16u* tB = P + ((size_t)(pb * 32) * 2048 + j0) * 64 + w * 2048 + lane * 8;
    b16u* lA = As + w * 2048;
    b16u* lB = Bs + w * 2048;

#define STAGE(IT, BUF)                                                    \
    {                                                                      \
        const b16u* ga = tA + (size_t)(IT) * 32768;                        \
        const b16u* gb = tB + (size_t)(IT) * 131072;                       \
        _Pragma("unroll")                                                  \
        for (int ch = 0; ch < 4; ++ch) {                                   \
            gl2lds16(ga + ch * 512, lA + (BUF) * 8192 + ch * 512);         \
            gl2lds16(gb + ch * 512, lB + (BUF) * 8192 + ch * 512);         \
        }                                                                  \
    }

    STAGE(0, 0)
    __syncthreads();

    floatx4 acc[4][4];
#pragma unroll
    for (int mt = 0; mt < 4; ++mt)
#pragma unroll
        for (int nt = 0; nt < 4; ++nt) acc[mt][nt] = (floatx4){0.f, 0.f, 0.f, 0.f};

    for (int it = 0; it < 32; ++it) {
        const int buf = it & 1;
        if (it < 31) STAGE(it + 1, buf ^ 1)
        const b16u* Ab = As + buf * 8192;
        const b16u* Bb = Bs + buf * 8192;
#pragma unroll
        for (int kc = 0; kc < 2; ++kc) {
            const int co = (((kc * 4 + qd) ^ (n16 & 7)) << 3);   // phys chunk offset
            short8 af[4], bf[4];
#pragma unroll
            for (int mt = 0; mt < 4; ++mt)
                af[mt] = *(const short8*)&Ab[(wc * 64 + mt * 16 + n16) * 64 + co];
#pragma unroll
            for (int nt = 0; nt < 4; ++nt)
                bf[nt] = *(const short8*)&Bb[(wj * 64 + nt * 16 + n16) * 64 + co];
#pragma unroll
            for (int mt = 0; mt < 4; ++mt)
#pragma unroll
                for (int nt = 0; nt < 4; ++nt)
                    acc[mt][nt] = MFMA16(af[mt], bf[nt], acc[mt][nt]);
        }
        __syncthreads();
    }
#undef STAGE

    // ---- epilogue: scale by g*zinv, stage per-wave quadrant, coalesced out ----
    const float g = gamma[0];
    float* st = (float*)(smem + w * 17408);       // 64 x 68 floats per wave
#pragma unroll
    for (int nt = 0; nt < 4; ++nt) {
        int j = j0 + wj * 64 + nt * 16 + n16;
        float zi = g / (Zpart[(size_t)b * 2048 + j] +
                        Zpart[16384 + (size_t)b * 2048 + j] +
                        Zpart[32768 + (size_t)b * 2048 + j] +
                        Zpart[49152 + (size_t)b * 2048 + j]);
#pragma unroll
        for (int mt = 0; mt < 4; ++mt)
#pragma unroll
            for (int r = 0; r < 4; ++r)
                st[(mt * 16 + qd * 4 + r) * 68 + nt * 16 + n16] = acc[mt][nt][r] * zi;
    }
    __syncthreads();
#pragma unroll
    for (int p = 0; p < 16; ++p) {
        int rl = qd * 16 + p;                     // c-local row in quadrant
        int cg = c0 + wc * 64 + rl;
        size_t go = ((size_t)(b * 512) + cg) * 2048 + j0 + wj * 64 + n16 * 4;
        float4 v = *(const float4*)&st[rl * 68 + n16 * 4];
        float4 xv = *(const float4*)(x + go);
        v.x += xv.x; v.y += xv.y; v.z += xv.z; v.w += xv.w;
        *(float4*)(out + go) = v;
    }
}

// ---------------------------------------------------------------------------
extern "C" void kernel_launch(void* const* d_in, const int* in_sizes, int n_in,
                              void* d_out, int out_size, void* d_ws, size_t ws_size,
                              hipStream_t stream)
{
    (void)in_sizes; (void)n_in; (void)out_size;
    const float* x     = (const float*)d_in[0];
    const float* W1    = (const float*)d_in[1];
    const float* W2    = (const float*)d_in[2];
    const float* gamma = (const float*)d_in[3];
    float* out = (float*)d_out;

    b16u*  Qt  = (b16u*)d_ws;                       // 2 MB
    b16u*  Kt  = Qt + (size_t)BB * LL * TT;         // 2 MB
    float* WT1 = (float*)(Kt + (size_t)BB * LL * TT);   // 128 KB
    float* WT2 = WT1 + (size_t)TT * CC;                 // 128 KB
    float* Zp  = WT2 + (size_t)TT * CC;             // 256 KB (4 partials)
    b16u*  XT  = (b16u*)(Zp + 4 * 8 * 2048);        // 16.8 MB
    b16u*  P   = XT + (size_t)BB * 32 * 512 * 64;   // nb * 8.39 MB

    const size_t base = (size_t)((char*)P - (char*)d_ws);
    const size_t pbat = (size_t)LL * LL * 2;
    int nb = 8;
    if (ws_size < base + 8 * pbat) nb = 4;
    if (ws_size < base + 4 * pbat) nb = 2;
    if (ws_size < base + 2 * pbat) nb = 1;

    wprep_kernel<<<dim3(128),       256, 0, stream>>>(W1, W2, WT1, WT2);
    qk_kernel   <<<dim3(512),       256, 0, stream>>>(x, WT1, WT2, Qt, Kt);
    xcvt_kernel <<<dim3(32, 8, BB), 256, 0, stream>>>(x, XT);
    for (int b0 = 0; b0 < BB; b0 += nb) {
        pexp_kernel<<<dim3(4, 32, nb), 256, 0, stream>>>(Qt, Kt, P, Zp, b0);
        gemm_kernel<<<dim3(16, 4, nb), 256, 0, stream>>>(x, XT, P, Zp, gamma, out, b0);
    }
}